// Round 1
// baseline (115.207 us; speedup 1.0000x reference)
//
#include <hip/hip_runtime.h>

// x:  [N=4, C=256, H=56, W=56] fp32
// w1: [N, 1, 32, 9,  H, W]     (3x3, pad 1)
// w2: [N, 1, 32, 25, H, W]     (5x5, pad 2)
// out:[N, 2, 1, C, H, W]
// out[n,b,c,h,w] = sum_p wB[n, c%32, p, h, w] * x[n, c, h+dh, w+dw] (zero pad)
//
// R9 = R8 with the gsel split REMOVED (weights were fetched 2x: both gsel
// halves of an (n,v,tile) read identical w1/w2 tap planes = 54.6 MB of pure
// over-fetch, 36% of kernel traffic). One block now owns all 8 channel
// groups of its (n,v,tile); to keep 1024 blocks (4/CU) the row tile halves
// (TILE 14->7, 8 tiles). 196 compute threads = (ghalf,row,s), each doing
// 4 of the 8 groups -> per-thread register/work footprint identical to R8.
//  - LDS: 8 planes x 11 rows x LSTRIDE 68 = 23936 B (4 blocks/CU = 95.7 KB).
//    LSTRIDE 68 (== 4 mod 32 banks) kept from R8's bank-conflict fix.
//  - Block order b = tile*128 + n*32 + v: the 8 tiles of one (n,v) are
//    128 apart == 0 mod 8 -> same XCD -> halo rows + x planes L2-hit.

#define N_  4
#define C_  256
#define H_  56
#define W_  56
#define HW_ 3136
#define WC_ 32

#define TILE    7
#define LROWS   11   // TILE + 4 halo rows
#define NPL     8    // all 8 channel groups staged
#define LSTRIDE 68   // x col c -> slot c+2; slots 0,1 & 58,59 zero halo

__global__ __launch_bounds__(256) void lconv_kernel(
    const float* __restrict__ x,
    const float* __restrict__ w1,
    const float* __restrict__ w2,
    float* __restrict__ out)
{
    __shared__ float lds[NPL * LROWS * LSTRIDE];   // 23936 B

    const int b    = blockIdx.x;        // 0..1023
    const int v    = b & 31;
    const int n    = (b >> 5) & 3;
    const int tile = b >> 7;            // 0..7; tiles of one (n,v) same XCD
    const int r0   = tile * TILE;
    const int nv   = n * WC_ + v;
    const int tid  = threadIdx.x;

    // ---- stage x: 8 planes x 11 rows x 56 cols; zero OOB rows ----
    for (int idx = tid; idx < NPL * LROWS * 14; idx += 256) {
        const int c4 = idx % 14;
        const int t2 = idx / 14;
        const int lr = t2 % LROWS;
        const int pl = t2 / LROWS;
        const int gr = r0 - 2 + lr;
        float4 val = make_float4(0.f, 0.f, 0.f, 0.f);
        if (gr >= 0 && gr < H_) {
            const int ch = pl * WC_ + v;
            val = *(const float4*)(x + (size_t)(n * C_ + ch) * HW_ + gr * W_ + c4 * 4);
        }
        float* lp = &lds[(pl * LROWS + lr) * LSTRIDE + 4 * c4 + 2];
        *(float2*)(lp)     = make_float2(val.x, val.y);
        *(float2*)(lp + 2) = make_float2(val.z, val.w);
    }
    // zero column halos: slots 0,1 (x cols -2,-1) and 58,59 (x cols 56,57)
    for (int idx = tid; idx < NPL * LROWS * 4; idx += 256) {
        const int k  = idx & 3;
        const int t2 = idx >> 2;
        const int lr = t2 % LROWS;
        const int pl = t2 / LROWS;
        const int slot = (k < 2) ? k : (56 + k);
        lds[(pl * LROWS + lr) * LSTRIDE + slot] = 0.f;
    }
    __syncthreads();

    if (tid >= 2 * TILE * 14) return;    // 196 compute threads; no barriers below

    const int ghalf = (tid >= TILE * 14) ? 1 : 0;
    const int t     = tid - ghalf * TILE * 14;
    const int row   = t / 14;            // 0..6
    const int s     = t - row * 14;
    const int wb    = 4 * s;             // 0,4,...,52
    const int gb    = ghalf * 4;         // group base: 0 or 4
    const int h     = r0 + row;
    const int hw    = h * W_ + wb;

    const float* w1t = w1 + (size_t)nv * 9  * HW_ + hw;
    const float* w2t = w2 + (size_t)nv * 25 * HW_ + hw;
    const int c0 = gb * WC_ + v;         // channel for g-index 0

    // ================= 5x5 branch: pipelined w2 stream =================
    float a2[4][4];
    #pragma unroll
    for (int g = 0; g < 4; ++g)
        #pragma unroll
        for (int p = 0; p < 4; ++p) a2[g][p] = 0.f;

    float4 w2cur[5], w2nxt[5];
    #pragma unroll
    for (int dj = 0; dj < 5; ++dj)
        w2cur[dj] = *(const float4*)(w2t + (size_t)dj * HW_);

    #pragma unroll 1
    for (int di = 0; di < 5; ++di) {
        if (di < 4) {
            #pragma unroll
            for (int dj = 0; dj < 5; ++dj)
                w2nxt[dj] = *(const float4*)(w2t + (size_t)((di + 1) * 5 + dj) * HW_);
        }
        #pragma unroll
        for (int g = 0; g < 4; ++g) {
            const float* lp = &lds[((gb + g) * LROWS + row + di) * LSTRIDE + wb];
            const float4 xa  = *(const float4*)(lp);
            const float4 xb4 = *(const float4*)(lp + 4);
            const float xw[8] = {xa.x, xa.y, xa.z, xa.w, xb4.x, xb4.y, xb4.z, xb4.w};
            #pragma unroll
            for (int dj = 0; dj < 5; ++dj) {
                const float* wr = (const float*)&w2cur[dj];
                #pragma unroll
                for (int p = 0; p < 4; ++p)
                    a2[g][p] += wr[p] * xw[p + dj];
            }
        }
        if (di < 4) {
            #pragma unroll
            for (int dj = 0; dj < 5; ++dj) w2cur[dj] = w2nxt[dj];
        }
    }

    float* o2 = out + ((size_t)(n * 2 + 1) * C_ + c0) * HW_ + hw;
    #pragma unroll
    for (int g = 0; g < 4; ++g)
        *(float4*)(o2 + (size_t)g * WC_ * HW_) =
            make_float4(a2[g][0], a2[g][1], a2[g][2], a2[g][3]);

    // ================= 3x3 branch: pipelined w1 stream =================
    float a1[4][4];
    #pragma unroll
    for (int g = 0; g < 4; ++g)
        #pragma unroll
        for (int p = 0; p < 4; ++p) a1[g][p] = 0.f;

    float4 w1cur[3], w1nxt[3];
    #pragma unroll
    for (int dj = 0; dj < 3; ++dj)
        w1cur[dj] = *(const float4*)(w1t + (size_t)dj * HW_);

    #pragma unroll 1
    for (int di = 0; di < 3; ++di) {
        if (di < 2) {
            #pragma unroll
            for (int dj = 0; dj < 3; ++dj)
                w1nxt[dj] = *(const float4*)(w1t + (size_t)((di + 1) * 3 + dj) * HW_);
        }
        #pragma unroll
        for (int g = 0; g < 4; ++g) {
            // x rows h-1+di -> LDS row row+1+di
            const float* lp = &lds[((gb + g) * LROWS + row + 1 + di) * LSTRIDE + wb];
            const float4 xa  = *(const float4*)(lp);
            const float4 xb4 = *(const float4*)(lp + 4);
            const float xw[8] = {xa.x, xa.y, xa.z, xa.w, xb4.x, xb4.y, xb4.z, xb4.w};
            #pragma unroll
            for (int dj = 0; dj < 3; ++dj) {
                const float* wr = (const float*)&w1cur[dj];
                #pragma unroll
                for (int p = 0; p < 4; ++p)
                    a1[g][p] += wr[p] * xw[p + dj + 1];
            }
        }
        if (di < 2) {
            #pragma unroll
            for (int dj = 0; dj < 3; ++dj) w1cur[dj] = w1nxt[dj];
        }
    }

    float* o1 = out + ((size_t)(n * 2 + 0) * C_ + c0) * HW_ + hw;
    #pragma unroll
    for (int g = 0; g < 4; ++g)
        *(float4*)(o1 + (size_t)g * WC_ * HW_) =
            make_float4(a1[g][0], a1[g][1], a1[g][2], a1[g][3]);
}

extern "C" void kernel_launch(void* const* d_in, const int* in_sizes, int n_in,
                              void* d_out, int out_size, void* d_ws, size_t ws_size,
                              hipStream_t stream) {
    const float* x  = (const float*)d_in[0];
    const float* w1 = (const float*)d_in[1];
    const float* w2 = (const float*)d_in[2];
    float* out = (float*)d_out;

    dim3 grid(1024), block(256);   // 4 blocks/CU
    hipLaunchKernelGGL(lconv_kernel, grid, block, 0, stream, x, w1, w2, out);
}